// Round 7
// baseline (187.757 us; speedup 1.0000x reference)
//
#include <hip/hip_runtime.h>
#include <cstdint>

// HypHawkes: attn = project(expmap0(softmax((project(expmap0(q))@W.T) @ project(expmap0(ctx)).T / d)))
// R7: no cooperative fusion (silent launch failure in r6). Four plain kernels:
//   prep_rows -> gemm_qw (64x64 tiles, 1024 blocks; occupancy fix for the small GEMM)
//   -> gemm_sc (r1-proven 128x128/BK=32 config) -> softmax_hyp (no max pass).

typedef unsigned short ushort_t;
typedef __bf16 bf16x8 __attribute__((ext_vector_type(8)));
typedef float f32x4 __attribute__((ext_vector_type(4)));

__device__ __forceinline__ unsigned short f32_to_bf16(float f) {
  unsigned int u = __float_as_uint(f);
  u = (u + 0x7fffu + ((u >> 16) & 1u)) >> 16;  // RNE; inputs are finite
  return (unsigned short)u;
}

__device__ __forceinline__ void async_copy16(const void* g, void* s) {
  __builtin_amdgcn_global_load_lds(
      (const __attribute__((address_space(1))) void*)g,
      (__attribute__((address_space(3))) void*)s, 16, 0, 0);
}

// ---------------- fused prep: rownorm+expmap+project for q/ctx, cvt for W ---
// blocks [0,n): q rows; [n,n+m): ctx rows; [n+m, ...): W cvt (1024 floats each)
__global__ void prep_rows(const float* __restrict__ q, const float* __restrict__ ctx,
                          const float* __restrict__ W, ushort_t* __restrict__ qn,
                          ushort_t* __restrict__ cn, ushort_t* __restrict__ Wb,
                          const float* __restrict__ cptr, int n, int m) {
  const int b = blockIdx.x;
  const int tid = threadIdx.x;

  if (b >= n + m) {  // W conversion chunk
    int i = (b - n - m) * 256 + tid;
    float4 v = reinterpret_cast<const float4*>(W)[i];
    reinterpret_cast<ushort4*>(Wb)[i] =
        make_ushort4(f32_to_bf16(v.x), f32_to_bf16(v.y), f32_to_bf16(v.z), f32_to_bf16(v.w));
    return;
  }

  const int lane = tid & 63, w = tid >> 6;
  __shared__ float red[4];
  const float* x = (b < n) ? q + (size_t)b * 1024 : ctx + (size_t)(b - n) * 1024;
  ushort_t* out = (b < n) ? qn + (size_t)b * 1024 : cn + (size_t)(b - n) * 1024;

  float4 v = reinterpret_cast<const float4*>(x)[tid];
  float ss = v.x * v.x + v.y * v.y + v.z * v.z + v.w * v.w;
#pragma unroll
  for (int o = 32; o; o >>= 1) ss += __shfl_down(ss, o, 64);
  if (lane == 0) red[w] = ss;
  __syncthreads();
  ss = red[0] + red[1] + red[2] + red[3];

  const float c = *cptr;
  const float sqrtc = sqrtf(c);
  const float norm = fmaxf(sqrtf(ss), 1e-5f);            // expmap0 u_norm clamp
  const float t = tanhf(sqrtc * norm) / (sqrtc * norm);  // expmap scale
  const float en = fmaxf(t * norm, 1e-5f);               // |expmap0(u)| (project clamp)
  const float maxn = (1.0f - 4e-3f) / sqrtc;
  const float s = t * (en > maxn ? maxn / en : 1.0f);

  reinterpret_cast<ushort4*>(out)[tid] =
      make_ushort4(f32_to_bf16(v.x * s), f32_to_bf16(v.y * s),
                   f32_to_bf16(v.z * s), f32_to_bf16(v.w * s));
}

// ---------------- gemm1: qw = qn @ Wb^T, bf16 out -------------------------
// TM=TN=64, BK=32 -> grid (64,16)=1024 blocks (4 blocks/CU: occupancy over
// per-block efficiency for this latency-bound 8.6 GFLOP GEMM; operands are
// L2/L3-resident). 4 waves 2x2, wave tile 32x32 (acc 2x2). 8KB LDS.
__global__ __launch_bounds__(256) void gemm_qw(const ushort_t* __restrict__ A,
                                               const ushort_t* __restrict__ B,
                                               ushort_t* __restrict__ Cb, int K, int N) {
  constexpr int ACH = 4, BCH = 4, CT = ACH + BCH, CPW = CT / 4;
  __shared__ __align__(16) ushort_t sm[CT * 512];

  const int tid = threadIdx.x;
  const int w = tid >> 6;
  const int lane = tid & 63;
  const int lane15 = lane & 15;
  const int quad = lane >> 4;
  const int wr = w >> 1, wc = w & 1;

  const int rowBase = blockIdx.x * 64;
  const int colBase = blockIdx.y * 64;
  const int srow = lane >> 2;
  const int scolE = (lane & 3) * 8;

  const ushort_t* gsrc[CPW];
  ushort_t* gdst[CPW];
#pragma unroll
  for (int i = 0; i < CPW; ++i) {
    int c = w * CPW + i;
    if (c < ACH)
      gsrc[i] = A + (size_t)(rowBase + c * 16 + srow) * K + scolE;
    else
      gsrc[i] = B + (size_t)(colBase + (c - ACH) * 16 + srow) * K + scolE;
    gdst[i] = sm + c * 512;
  }

  f32x4 acc[2][2];
#pragma unroll
  for (int i = 0; i < 2; ++i)
#pragma unroll
    for (int j = 0; j < 2; ++j) acc[i][j] = f32x4{0.f, 0.f, 0.f, 0.f};

  for (int k0 = 0; k0 < K; k0 += 32) {
#pragma unroll
    for (int i = 0; i < CPW; ++i) async_copy16(gsrc[i] + k0, gdst[i]);
    __syncthreads();
    bf16x8 af[2], bv[2];
#pragma unroll
    for (int i = 0; i < 2; ++i)
      af[i] = *reinterpret_cast<const bf16x8*>(&sm[(wr * 2 + i) * 512 + lane15 * 32 + quad * 8]);
#pragma unroll
    for (int j = 0; j < 2; ++j)
      bv[j] = *reinterpret_cast<const bf16x8*>(
          &sm[(ACH + wc * 2 + j) * 512 + lane15 * 32 + quad * 8]);
#pragma unroll
    for (int i = 0; i < 2; ++i)
#pragma unroll
      for (int j = 0; j < 2; ++j)
        acc[i][j] = __builtin_amdgcn_mfma_f32_16x16x32_bf16(af[i], bv[j], acc[i][j], 0, 0, 0);
    __syncthreads();
  }

  // C/D layout: col = lane&15, row = quad*4 + reg
#pragma unroll
  for (int i = 0; i < 2; ++i)
#pragma unroll
    for (int j = 0; j < 2; ++j)
#pragma unroll
      for (int r = 0; r < 4; ++r) {
        int row = rowBase + wr * 32 + i * 16 + quad * 4 + r;
        int col = colBase + wc * 32 + j * 16 + lane15;
        Cb[(size_t)row * N + col] = f32_to_bf16(acc[i][j][r]);
      }
}

// ---------------- gemm2: scores = qw @ cn^T, fp32 out ----------------------
// r1-proven config: TM=TN=128, BK=32, 16KB LDS, 4 waves 2x2, wave 64x64 (acc 4x4).
// LDS bank conflicts (~4M) are hidden under staging latency — measured fastest.
__global__ __launch_bounds__(256) void gemm_sc(const ushort_t* __restrict__ A,
                                               const ushort_t* __restrict__ B,
                                               float* __restrict__ Cf, int K, int N) {
  constexpr int ACH = 8, BCH = 8, CT = ACH + BCH, CPW = CT / 4;
  __shared__ __align__(16) ushort_t sm[CT * 512];

  const int tid = threadIdx.x;
  const int w = tid >> 6;
  const int lane = tid & 63;
  const int lane15 = lane & 15;
  const int quad = lane >> 4;
  const int wr = w >> 1, wc = w & 1;

  const int rowBase = blockIdx.x * 128;
  const int colBase = blockIdx.y * 128;
  const int srow = lane >> 2;
  const int scolE = (lane & 3) * 8;

  const ushort_t* gsrc[CPW];
  ushort_t* gdst[CPW];
#pragma unroll
  for (int i = 0; i < CPW; ++i) {
    int c = w * CPW + i;
    if (c < ACH)
      gsrc[i] = A + (size_t)(rowBase + c * 16 + srow) * K + scolE;
    else
      gsrc[i] = B + (size_t)(colBase + (c - ACH) * 16 + srow) * K + scolE;
    gdst[i] = sm + c * 512;
  }

  f32x4 acc[4][4];
#pragma unroll
  for (int i = 0; i < 4; ++i)
#pragma unroll
    for (int j = 0; j < 4; ++j) acc[i][j] = f32x4{0.f, 0.f, 0.f, 0.f};

  for (int k0 = 0; k0 < K; k0 += 32) {
#pragma unroll
    for (int i = 0; i < CPW; ++i) async_copy16(gsrc[i] + k0, gdst[i]);
    __syncthreads();
    bf16x8 af[4], bv[4];
#pragma unroll
    for (int i = 0; i < 4; ++i)
      af[i] = *reinterpret_cast<const bf16x8*>(&sm[(wr * 4 + i) * 512 + lane15 * 32 + quad * 8]);
#pragma unroll
    for (int j = 0; j < 4; ++j)
      bv[j] = *reinterpret_cast<const bf16x8*>(
          &sm[(ACH + wc * 4 + j) * 512 + lane15 * 32 + quad * 8]);
#pragma unroll
    for (int i = 0; i < 4; ++i)
#pragma unroll
      for (int j = 0; j < 4; ++j)
        acc[i][j] = __builtin_amdgcn_mfma_f32_16x16x32_bf16(af[i], bv[j], acc[i][j], 0, 0, 0);
    __syncthreads();
  }

#pragma unroll
  for (int i = 0; i < 4; ++i)
#pragma unroll
    for (int j = 0; j < 4; ++j)
#pragma unroll
      for (int r = 0; r < 4; ++r) {
        int row = rowBase + wr * 64 + i * 16 + quad * 4 + r;
        int col = colBase + wc * 64 + j * 16 + lane15;
        Cf[(size_t)row * N + col] = acc[i][j][r];
      }
}

// ---------------- in-place softmax(row/d) + expmap0 + project --------------
// No max pass: logits = scores/1024 are ~+/-2e-3; exp cannot overflow and
// max-subtraction is numerically irrelevant at the 2% output tolerance.
__global__ void softmax_hyp(float* __restrict__ S, const float* __restrict__ cptr,
                            float invd) {
  const int tid = threadIdx.x;
  const int lane = tid & 63, w = tid >> 6;
  __shared__ float redS[4], redQ[4];
  float* rp = S + (size_t)blockIdx.x * 4096;

  float4 v[4];
#pragma unroll
  for (int i = 0; i < 4; ++i) v[i] = reinterpret_cast<float4*>(rp)[i * 256 + tid];

  float sum = 0.f, sq = 0.f;
#pragma unroll
  for (int i = 0; i < 4; ++i) {
    v[i].x = __expf(v[i].x * invd); v[i].y = __expf(v[i].y * invd);
    v[i].z = __expf(v[i].z * invd); v[i].w = __expf(v[i].w * invd);
    sum += v[i].x + v[i].y + v[i].z + v[i].w;
    sq += v[i].x * v[i].x + v[i].y * v[i].y + v[i].z * v[i].z + v[i].w * v[i].w;
  }
#pragma unroll
  for (int o = 32; o; o >>= 1) {
    sum += __shfl_down(sum, o, 64);
    sq += __shfl_down(sq, o, 64);
  }
  if (lane == 0) { redS[w] = sum; redQ[w] = sq; }
  __syncthreads();
  sum = redS[0] + redS[1] + redS[2] + redS[3];
  sq = redQ[0] + redQ[1] + redQ[2] + redQ[3];

  const float c = *cptr;
  const float sqrtc = sqrtf(c);
  const float anorm = sqrtf(sq) / sum;       // |attn|
  const float an = fmaxf(anorm, 1e-5f);      // expmap0 clamp
  const float t = tanhf(sqrtc * an) / (sqrtc * an);
  const float pn = fmaxf(t * anorm, 1e-5f);  // |expmap0(attn)| (project clamp)
  const float maxn = (1.0f - 4e-3f) / sqrtc;
  const float g = t * (pn > maxn ? maxn / pn : 1.0f) / sum;

#pragma unroll
  for (int i = 0; i < 4; ++i) {
    v[i].x *= g; v[i].y *= g; v[i].z *= g; v[i].w *= g;
    reinterpret_cast<float4*>(rp)[i * 256 + tid] = v[i];
  }
}

extern "C" void kernel_launch(void* const* d_in, const int* in_sizes, int n_in,
                              void* d_out, int out_size, void* d_ws, size_t ws_size,
                              hipStream_t stream) {
  const float* query = (const float*)d_in[0];
  const float* context = (const float*)d_in[1];
  const float* W = (const float*)d_in[2];
  const float* cptr = (const float*)d_in[3];

  const int d = 1024;
  const int n = in_sizes[0] / d;  // 4096
  const int m = in_sizes[1] / d;  // 4096

  ushort_t* qn = (ushort_t*)d_ws;     // n*d bf16, row-major
  ushort_t* cn = qn + (size_t)n * d;  // m*d
  ushort_t* Wb = cn + (size_t)m * d;  // d*d
  ushort_t* qw = Wb + (size_t)d * d;  // n*d
  float* scores = (float*)d_out;      // n*m fp32, softmaxed in place

  prep_rows<<<n + m + d * d / 1024, 256, 0, stream>>>(query, context, W, qn, cn, Wb, cptr, n, m);
  // qw = qn @ Wb^T : grid (64,16)=1024 blocks
  gemm_qw<<<dim3(n / 64, d / 64), 256, 0, stream>>>(qn, Wb, qw, d, d);
  // scores = qw @ cn^T : grid (32,32)=1024 blocks
  gemm_sc<<<dim3(n / 128, m / 128), 256, 0, stream>>>(qw, cn, scores, d, m);
  softmax_hyp<<<n, 256, 0, stream>>>(scores, cptr, 1.0f / (float)d);
}

// Round 8
// 186.847 us; speedup vs baseline: 1.0049x; 1.0049x over previous
//
#include <hip/hip_runtime.h>
#include <cstdint>

// HypHawkes: attn = project(expmap0(softmax((project(expmap0(q))@W.T) @ project(expmap0(ctx)).T / d)))
// R8: both GEMMs restored to the r1 staging CODE SHAPE — two base pointers with
// immediate offsets (NOT indexed pointer arrays: r3/r7 showed the array form costs
// +12 VGPR and 3.6x K-loop VALU time regardless of global layout).
//   prep_rows -> gemm_qw (64x64, BK=32, 1024 blocks) -> gemm_sc (128x128, BK=32,
//   r1-proven 48us) -> softmax_hyp (no max pass).

typedef unsigned short ushort_t;
typedef __bf16 bf16x8 __attribute__((ext_vector_type(8)));
typedef float f32x4 __attribute__((ext_vector_type(4)));

__device__ __forceinline__ unsigned short f32_to_bf16(float f) {
  unsigned int u = __float_as_uint(f);
  u = (u + 0x7fffu + ((u >> 16) & 1u)) >> 16;  // RNE; inputs are finite
  return (unsigned short)u;
}

__device__ __forceinline__ void async_copy16(const void* g, void* s) {
  __builtin_amdgcn_global_load_lds(
      (const __attribute__((address_space(1))) void*)g,
      (__attribute__((address_space(3))) void*)s, 16, 0, 0);
}

// ---------------- fused prep: rownorm+expmap+project for q/ctx, cvt for W ---
// blocks [0,n): q rows; [n,n+m): ctx rows; [n+m, ...): W cvt (1024 floats each)
__global__ void prep_rows(const float* __restrict__ q, const float* __restrict__ ctx,
                          const float* __restrict__ W, ushort_t* __restrict__ qn,
                          ushort_t* __restrict__ cn, ushort_t* __restrict__ Wb,
                          const float* __restrict__ cptr, int n, int m) {
  const int b = blockIdx.x;
  const int tid = threadIdx.x;

  if (b >= n + m) {  // W conversion chunk
    int i = (b - n - m) * 256 + tid;
    float4 v = reinterpret_cast<const float4*>(W)[i];
    reinterpret_cast<ushort4*>(Wb)[i] =
        make_ushort4(f32_to_bf16(v.x), f32_to_bf16(v.y), f32_to_bf16(v.z), f32_to_bf16(v.w));
    return;
  }

  const int lane = tid & 63, w = tid >> 6;
  __shared__ float red[4];
  const float* x = (b < n) ? q + (size_t)b * 1024 : ctx + (size_t)(b - n) * 1024;
  ushort_t* out = (b < n) ? qn + (size_t)b * 1024 : cn + (size_t)(b - n) * 1024;

  float4 v = reinterpret_cast<const float4*>(x)[tid];
  float ss = v.x * v.x + v.y * v.y + v.z * v.z + v.w * v.w;
#pragma unroll
  for (int o = 32; o; o >>= 1) ss += __shfl_down(ss, o, 64);
  if (lane == 0) red[w] = ss;
  __syncthreads();
  ss = red[0] + red[1] + red[2] + red[3];

  const float c = *cptr;
  const float sqrtc = sqrtf(c);
  const float norm = fmaxf(sqrtf(ss), 1e-5f);            // expmap0 u_norm clamp
  const float t = tanhf(sqrtc * norm) / (sqrtc * norm);  // expmap scale
  const float en = fmaxf(t * norm, 1e-5f);               // |expmap0(u)| (project clamp)
  const float maxn = (1.0f - 4e-3f) / sqrtc;
  const float s = t * (en > maxn ? maxn / en : 1.0f);

  reinterpret_cast<ushort4*>(out)[tid] =
      make_ushort4(f32_to_bf16(v.x * s), f32_to_bf16(v.y * s),
                   f32_to_bf16(v.z * s), f32_to_bf16(v.w * s));
}

// ---------------- gemm1: qw = qn @ Wb^T, bf16 out -------------------------
// TM=TN=64, BK=32, grid (64,16)=1024 blocks. r1-style inline staging: wave w
// stages A-chunk w and B-chunk w (16 rows x 32 cols each). 8KB LDS.
__global__ __launch_bounds__(256) void gemm_qw(const ushort_t* __restrict__ A,
                                               const ushort_t* __restrict__ B,
                                               ushort_t* __restrict__ Cb, int K, int N) {
  __shared__ __align__(16) ushort_t As[64 * 32];
  __shared__ __align__(16) ushort_t Bs[64 * 32];

  const int tid = threadIdx.x;
  const int w = tid >> 6;
  const int lane = tid & 63;
  const int lane15 = lane & 15;
  const int quad = lane >> 4;
  const int wr = w >> 1, wc = w & 1;

  const size_t rowBase = (size_t)blockIdx.x * 64;
  const size_t colBase = (size_t)blockIdx.y * 64;

  const int srow = lane >> 2;        // 0..15
  const int scolE = (lane & 3) * 8;  // 0,8,16,24
  const ushort_t* Ag = A + (rowBase + (size_t)(w * 16 + srow)) * K + scolE;
  const ushort_t* Bg = B + (colBase + (size_t)(w * 16 + srow)) * K + scolE;
  ushort_t* AsD = &As[w * 512];
  ushort_t* BsD = &Bs[w * 512];

  f32x4 acc[2][2];
#pragma unroll
  for (int i = 0; i < 2; ++i)
#pragma unroll
    for (int j = 0; j < 2; ++j) acc[i][j] = f32x4{0.f, 0.f, 0.f, 0.f};

  for (int k0 = 0; k0 < K; k0 += 32) {
    async_copy16(Ag + k0, AsD);
    async_copy16(Bg + k0, BsD);
    __syncthreads();

    bf16x8 af[2], bv[2];
#pragma unroll
    for (int i = 0; i < 2; ++i) {
      af[i] = *reinterpret_cast<const bf16x8*>(&As[(wr * 32 + i * 16 + lane15) * 32 + quad * 8]);
      bv[i] = *reinterpret_cast<const bf16x8*>(&Bs[(wc * 32 + i * 16 + lane15) * 32 + quad * 8]);
    }
#pragma unroll
    for (int i = 0; i < 2; ++i)
#pragma unroll
      for (int j = 0; j < 2; ++j)
        acc[i][j] = __builtin_amdgcn_mfma_f32_16x16x32_bf16(af[i], bv[j], acc[i][j], 0, 0, 0);
    __syncthreads();
  }

  // C/D layout: col = lane&15, row = quad*4 + reg
#pragma unroll
  for (int i = 0; i < 2; ++i)
#pragma unroll
    for (int j = 0; j < 2; ++j)
#pragma unroll
      for (int r = 0; r < 4; ++r) {
        size_t row = rowBase + (size_t)(wr * 32 + i * 16 + quad * 4 + r);
        size_t col = colBase + (size_t)(wc * 32 + j * 16 + lane15);
        Cb[row * N + col] = f32_to_bf16(acc[i][j][r]);
      }
}

// ---------------- gemm2: scores = qw @ cn^T, fp32 out ----------------------
// Literal r1 structure (measured 48us, VGPR 56, VALUBusy 15%): TM=TN=128, BK=32,
// 16KB LDS, wave w stages A-chunks {2w,2w+1} then B-chunks {2w,2w+1} from two
// base pointers with immediate offsets. LDS conflicts (~4M) hidden under staging.
__global__ __launch_bounds__(256) void gemm_sc(const ushort_t* __restrict__ A,
                                               const ushort_t* __restrict__ B,
                                               float* __restrict__ Cf, int K, int N) {
  __shared__ __align__(16) ushort_t As[128 * 32];
  __shared__ __align__(16) ushort_t Bs[128 * 32];

  const int tid = threadIdx.x;
  const int w = tid >> 6;
  const int lane = tid & 63;
  const int lane15 = lane & 15;
  const int quad = lane >> 4;
  const int wr = w >> 1, wc = w & 1;

  const size_t rowBase = (size_t)blockIdx.x * 128;
  const size_t colBase = (size_t)blockIdx.y * 128;

  const int srow = lane >> 2;        // 0..15
  const int scolE = (lane & 3) * 8;  // 0,8,16,24
  const ushort_t* Ag = A + (rowBase + (size_t)(w * 32 + srow)) * K + scolE;
  const ushort_t* Bg = B + (colBase + (size_t)(w * 32 + srow)) * K + scolE;
  ushort_t* AsD = &As[(w * 2) * 512];
  ushort_t* BsD = &Bs[(w * 2) * 512];

  f32x4 acc[4][4];
#pragma unroll
  for (int i = 0; i < 4; ++i)
#pragma unroll
    for (int j = 0; j < 4; ++j) acc[i][j] = f32x4{0.f, 0.f, 0.f, 0.f};

  for (int k0 = 0; k0 < K; k0 += 32) {
    async_copy16(Ag + k0, AsD);
    async_copy16(Ag + (size_t)16 * K + k0, AsD + 512);
    async_copy16(Bg + k0, BsD);
    async_copy16(Bg + (size_t)16 * K + k0, BsD + 512);
    __syncthreads();

    bf16x8 af[4], bv[4];
#pragma unroll
    for (int i = 0; i < 4; ++i) {
      af[i] = *reinterpret_cast<const bf16x8*>(&As[(wr * 64 + i * 16 + lane15) * 32 + quad * 8]);
      bv[i] = *reinterpret_cast<const bf16x8*>(&Bs[(wc * 64 + i * 16 + lane15) * 32 + quad * 8]);
    }
#pragma unroll
    for (int i = 0; i < 4; ++i)
#pragma unroll
      for (int j = 0; j < 4; ++j)
        acc[i][j] = __builtin_amdgcn_mfma_f32_16x16x32_bf16(af[i], bv[j], acc[i][j], 0, 0, 0);
    __syncthreads();
  }

  // C/D layout: col = lane&15, row = quad*4 + reg
#pragma unroll
  for (int i = 0; i < 4; ++i)
#pragma unroll
    for (int j = 0; j < 4; ++j)
#pragma unroll
      for (int r = 0; r < 4; ++r) {
        size_t row = rowBase + (size_t)(wr * 64 + i * 16 + quad * 4 + r);
        size_t col = colBase + (size_t)(wc * 64 + j * 16 + lane15);
        Cf[row * N + col] = acc[i][j][r];
      }
}

// ---------------- in-place softmax(row/d) + expmap0 + project --------------
// No max pass: logits = scores/1024 are ~+/-2e-3; exp cannot overflow and
// max-subtraction is numerically irrelevant at the output tolerance.
__global__ void softmax_hyp(float* __restrict__ S, const float* __restrict__ cptr,
                            float invd) {
  const int tid = threadIdx.x;
  const int lane = tid & 63, w = tid >> 6;
  __shared__ float redS[4], redQ[4];
  float* rp = S + (size_t)blockIdx.x * 4096;

  float4 v[4];
#pragma unroll
  for (int i = 0; i < 4; ++i) v[i] = reinterpret_cast<float4*>(rp)[i * 256 + tid];

  float sum = 0.f, sq = 0.f;
#pragma unroll
  for (int i = 0; i < 4; ++i) {
    v[i].x = __expf(v[i].x * invd); v[i].y = __expf(v[i].y * invd);
    v[i].z = __expf(v[i].z * invd); v[i].w = __expf(v[i].w * invd);
    sum += v[i].x + v[i].y + v[i].z + v[i].w;
    sq += v[i].x * v[i].x + v[i].y * v[i].y + v[i].z * v[i].z + v[i].w * v[i].w;
  }
#pragma unroll
  for (int o = 32; o; o >>= 1) {
    sum += __shfl_down(sum, o, 64);
    sq += __shfl_down(sq, o, 64);
  }
  if (lane == 0) { redS[w] = sum; redQ[w] = sq; }
  __syncthreads();
  sum = redS[0] + redS[1] + redS[2] + redS[3];
  sq = redQ[0] + redQ[1] + redQ[2] + redQ[3];

  const float c = *cptr;
  const float sqrtc = sqrtf(c);
  const float anorm = sqrtf(sq) / sum;       // |attn|
  const float an = fmaxf(anorm, 1e-5f);      // expmap0 clamp
  const float t = tanhf(sqrtc * an) / (sqrtc * an);
  const float pn = fmaxf(t * anorm, 1e-5f);  // |expmap0(attn)| (project clamp)
  const float maxn = (1.0f - 4e-3f) / sqrtc;
  const float g = t * (pn > maxn ? maxn / pn : 1.0f) / sum;

#pragma unroll
  for (int i = 0; i < 4; ++i) {
    v[i].x *= g; v[i].y *= g; v[i].z *= g; v[i].w *= g;
    reinterpret_cast<float4*>(rp)[i * 256 + tid] = v[i];
  }
}

extern "C" void kernel_launch(void* const* d_in, const int* in_sizes, int n_in,
                              void* d_out, int out_size, void* d_ws, size_t ws_size,
                              hipStream_t stream) {
  const float* query = (const float*)d_in[0];
  const float* context = (const float*)d_in[1];
  const float* W = (const float*)d_in[2];
  const float* cptr = (const float*)d_in[3];

  const int d = 1024;
  const int n = in_sizes[0] / d;  // 4096
  const int m = in_sizes[1] / d;  // 4096

  ushort_t* qn = (ushort_t*)d_ws;     // n*d bf16, row-major
  ushort_t* cn = qn + (size_t)n * d;  // m*d
  ushort_t* Wb = cn + (size_t)m * d;  // d*d
  ushort_t* qw = Wb + (size_t)d * d;  // n*d
  float* scores = (float*)d_out;      // n*m fp32, softmaxed in place

  prep_rows<<<n + m + d * d / 1024, 256, 0, stream>>>(query, context, W, qn, cn, Wb, cptr, n, m);
  // qw = qn @ Wb^T : grid (64,16)=1024 blocks
  gemm_qw<<<dim3(n / 64, d / 64), 256, 0, stream>>>(qn, Wb, qw, d, d);
  // scores = qw @ cn^T : grid (32,32)=1024 blocks
  gemm_sc<<<dim3(n / 128, m / 128), 256, 0, stream>>>(qw, cn, scores, d, m);
  softmax_hyp<<<n, 256, 0, stream>>>(scores, cptr, 1.0f / (float)d);
}

// Round 9
// 173.370 us; speedup vs baseline: 1.0830x; 1.0777x over previous
//
#include <hip/hip_runtime.h>
#include <cstdint>

// HypHawkes: attn = project(expmap0(softmax((project(expmap0(q))@W.T) @ project(expmap0(ctx)).T / d)))
// R9: identical to R8 EXCEPT __launch_bounds__ removed from both GEMMs.
// Evidence: r1 (no LB) compiled to VGPR=56/VALUBusy=15%/48us; r3/r5/r7/r8 (LB 256)
// all compiled to VGPR>=68/VALUBusy>=29% regardless of staging style. The LB(256)
// attribute relaxes the default 1024-thread VGPR cap and makes the scheduler
// allocate longer live ranges — net loss for this kernel. Keep everything else frozen.

typedef unsigned short ushort_t;
typedef __bf16 bf16x8 __attribute__((ext_vector_type(8)));
typedef float f32x4 __attribute__((ext_vector_type(4)));

__device__ __forceinline__ unsigned short f32_to_bf16(float f) {
  unsigned int u = __float_as_uint(f);
  u = (u + 0x7fffu + ((u >> 16) & 1u)) >> 16;  // RNE; inputs are finite
  return (unsigned short)u;
}

__device__ __forceinline__ void async_copy16(const void* g, void* s) {
  __builtin_amdgcn_global_load_lds(
      (const __attribute__((address_space(1))) void*)g,
      (__attribute__((address_space(3))) void*)s, 16, 0, 0);
}

// ---------------- fused prep: rownorm+expmap+project for q/ctx, cvt for W ---
// blocks [0,n): q rows; [n,n+m): ctx rows; [n+m, ...): W cvt (1024 floats each)
__global__ void prep_rows(const float* __restrict__ q, const float* __restrict__ ctx,
                          const float* __restrict__ W, ushort_t* __restrict__ qn,
                          ushort_t* __restrict__ cn, ushort_t* __restrict__ Wb,
                          const float* __restrict__ cptr, int n, int m) {
  const int b = blockIdx.x;
  const int tid = threadIdx.x;

  if (b >= n + m) {  // W conversion chunk
    int i = (b - n - m) * 256 + tid;
    float4 v = reinterpret_cast<const float4*>(W)[i];
    reinterpret_cast<ushort4*>(Wb)[i] =
        make_ushort4(f32_to_bf16(v.x), f32_to_bf16(v.y), f32_to_bf16(v.z), f32_to_bf16(v.w));
    return;
  }

  const int lane = tid & 63, w = tid >> 6;
  __shared__ float red[4];
  const float* x = (b < n) ? q + (size_t)b * 1024 : ctx + (size_t)(b - n) * 1024;
  ushort_t* out = (b < n) ? qn + (size_t)b * 1024 : cn + (size_t)(b - n) * 1024;

  float4 v = reinterpret_cast<const float4*>(x)[tid];
  float ss = v.x * v.x + v.y * v.y + v.z * v.z + v.w * v.w;
#pragma unroll
  for (int o = 32; o; o >>= 1) ss += __shfl_down(ss, o, 64);
  if (lane == 0) red[w] = ss;
  __syncthreads();
  ss = red[0] + red[1] + red[2] + red[3];

  const float c = *cptr;
  const float sqrtc = sqrtf(c);
  const float norm = fmaxf(sqrtf(ss), 1e-5f);            // expmap0 u_norm clamp
  const float t = tanhf(sqrtc * norm) / (sqrtc * norm);  // expmap scale
  const float en = fmaxf(t * norm, 1e-5f);               // |expmap0(u)| (project clamp)
  const float maxn = (1.0f - 4e-3f) / sqrtc;
  const float s = t * (en > maxn ? maxn / en : 1.0f);

  reinterpret_cast<ushort4*>(out)[tid] =
      make_ushort4(f32_to_bf16(v.x * s), f32_to_bf16(v.y * s),
                   f32_to_bf16(v.z * s), f32_to_bf16(v.w * s));
}

// ---------------- gemm1: qw = qn @ Wb^T, bf16 out -------------------------
// TM=TN=64, BK=32, grid (64,16)=1024 blocks. r1-style inline staging: wave w
// stages A-chunk w and B-chunk w (16 rows x 32 cols each). 8KB LDS. NO launch_bounds.
__global__ void gemm_qw(const ushort_t* __restrict__ A,
                        const ushort_t* __restrict__ B,
                        ushort_t* __restrict__ Cb, int K, int N) {
  __shared__ __align__(16) ushort_t As[64 * 32];
  __shared__ __align__(16) ushort_t Bs[64 * 32];

  const int tid = threadIdx.x;
  const int w = tid >> 6;
  const int lane = tid & 63;
  const int lane15 = lane & 15;
  const int quad = lane >> 4;
  const int wr = w >> 1, wc = w & 1;

  const size_t rowBase = (size_t)blockIdx.x * 64;
  const size_t colBase = (size_t)blockIdx.y * 64;

  const int srow = lane >> 2;        // 0..15
  const int scolE = (lane & 3) * 8;  // 0,8,16,24
  const ushort_t* Ag = A + (rowBase + (size_t)(w * 16 + srow)) * K + scolE;
  const ushort_t* Bg = B + (colBase + (size_t)(w * 16 + srow)) * K + scolE;
  ushort_t* AsD = &As[w * 512];
  ushort_t* BsD = &Bs[w * 512];

  f32x4 acc[2][2];
#pragma unroll
  for (int i = 0; i < 2; ++i)
#pragma unroll
    for (int j = 0; j < 2; ++j) acc[i][j] = f32x4{0.f, 0.f, 0.f, 0.f};

  for (int k0 = 0; k0 < K; k0 += 32) {
    async_copy16(Ag + k0, AsD);
    async_copy16(Bg + k0, BsD);
    __syncthreads();

    bf16x8 af[2], bv[2];
#pragma unroll
    for (int i = 0; i < 2; ++i) {
      af[i] = *reinterpret_cast<const bf16x8*>(&As[(wr * 32 + i * 16 + lane15) * 32 + quad * 8]);
      bv[i] = *reinterpret_cast<const bf16x8*>(&Bs[(wc * 32 + i * 16 + lane15) * 32 + quad * 8]);
    }
#pragma unroll
    for (int i = 0; i < 2; ++i)
#pragma unroll
      for (int j = 0; j < 2; ++j)
        acc[i][j] = __builtin_amdgcn_mfma_f32_16x16x32_bf16(af[i], bv[j], acc[i][j], 0, 0, 0);
    __syncthreads();
  }

  // C/D layout: col = lane&15, row = quad*4 + reg
#pragma unroll
  for (int i = 0; i < 2; ++i)
#pragma unroll
    for (int j = 0; j < 2; ++j)
#pragma unroll
      for (int r = 0; r < 4; ++r) {
        size_t row = rowBase + (size_t)(wr * 32 + i * 16 + quad * 4 + r);
        size_t col = colBase + (size_t)(wc * 32 + j * 16 + lane15);
        Cb[row * N + col] = f32_to_bf16(acc[i][j][r]);
      }
}

// ---------------- gemm2: scores = qw @ cn^T, fp32 out ----------------------
// Literal r1 structure (measured 48us, VGPR 56, VALUBusy 15%): TM=TN=128, BK=32,
// 16KB LDS, wave w stages A-chunks {2w,2w+1} then B-chunks {2w,2w+1} from two
// base pointers with immediate offsets. NO launch_bounds (the r7/r8 regression).
__global__ void gemm_sc(const ushort_t* __restrict__ A,
                        const ushort_t* __restrict__ B,
                        float* __restrict__ Cf, int K, int N) {
  __shared__ __align__(16) ushort_t As[128 * 32];
  __shared__ __align__(16) ushort_t Bs[128 * 32];

  const int tid = threadIdx.x;
  const int w = tid >> 6;
  const int lane = tid & 63;
  const int lane15 = lane & 15;
  const int quad = lane >> 4;
  const int wr = w >> 1, wc = w & 1;

  const size_t rowBase = (size_t)blockIdx.x * 128;
  const size_t colBase = (size_t)blockIdx.y * 128;

  const int srow = lane >> 2;        // 0..15
  const int scolE = (lane & 3) * 8;  // 0,8,16,24
  const ushort_t* Ag = A + (rowBase + (size_t)(w * 32 + srow)) * K + scolE;
  const ushort_t* Bg = B + (colBase + (size_t)(w * 32 + srow)) * K + scolE;
  ushort_t* AsD = &As[(w * 2) * 512];
  ushort_t* BsD = &Bs[(w * 2) * 512];

  f32x4 acc[4][4];
#pragma unroll
  for (int i = 0; i < 4; ++i)
#pragma unroll
    for (int j = 0; j < 4; ++j) acc[i][j] = f32x4{0.f, 0.f, 0.f, 0.f};

  for (int k0 = 0; k0 < K; k0 += 32) {
    async_copy16(Ag + k0, AsD);
    async_copy16(Ag + (size_t)16 * K + k0, AsD + 512);
    async_copy16(Bg + k0, BsD);
    async_copy16(Bg + (size_t)16 * K + k0, BsD + 512);
    __syncthreads();

    bf16x8 af[4], bv[4];
#pragma unroll
    for (int i = 0; i < 4; ++i) {
      af[i] = *reinterpret_cast<const bf16x8*>(&As[(wr * 64 + i * 16 + lane15) * 32 + quad * 8]);
      bv[i] = *reinterpret_cast<const bf16x8*>(&Bs[(wc * 64 + i * 16 + lane15) * 32 + quad * 8]);
    }
#pragma unroll
    for (int i = 0; i < 4; ++i)
#pragma unroll
      for (int j = 0; j < 4; ++j)
        acc[i][j] = __builtin_amdgcn_mfma_f32_16x16x32_bf16(af[i], bv[j], acc[i][j], 0, 0, 0);
    __syncthreads();
  }

  // C/D layout: col = lane&15, row = quad*4 + reg
#pragma unroll
  for (int i = 0; i < 4; ++i)
#pragma unroll
    for (int j = 0; j < 4; ++j)
#pragma unroll
      for (int r = 0; r < 4; ++r) {
        size_t row = rowBase + (size_t)(wr * 64 + i * 16 + quad * 4 + r);
        size_t col = colBase + (size_t)(wc * 64 + j * 16 + lane15);
        Cf[row * N + col] = acc[i][j][r];
      }
}

// ---------------- in-place softmax(row/d) + expmap0 + project --------------
// No max pass: logits = scores/1024 are ~+/-2e-3; exp cannot overflow and
// max-subtraction is numerically irrelevant at the output tolerance.
__global__ void softmax_hyp(float* __restrict__ S, const float* __restrict__ cptr,
                            float invd) {
  const int tid = threadIdx.x;
  const int lane = tid & 63, w = tid >> 6;
  __shared__ float redS[4], redQ[4];
  float* rp = S + (size_t)blockIdx.x * 4096;

  float4 v[4];
#pragma unroll
  for (int i = 0; i < 4; ++i) v[i] = reinterpret_cast<float4*>(rp)[i * 256 + tid];

  float sum = 0.f, sq = 0.f;
#pragma unroll
  for (int i = 0; i < 4; ++i) {
    v[i].x = __expf(v[i].x * invd); v[i].y = __expf(v[i].y * invd);
    v[i].z = __expf(v[i].z * invd); v[i].w = __expf(v[i].w * invd);
    sum += v[i].x + v[i].y + v[i].z + v[i].w;
    sq += v[i].x * v[i].x + v[i].y * v[i].y + v[i].z * v[i].z + v[i].w * v[i].w;
  }
#pragma unroll
  for (int o = 32; o; o >>= 1) {
    sum += __shfl_down(sum, o, 64);
    sq += __shfl_down(sq, o, 64);
  }
  if (lane == 0) { redS[w] = sum; redQ[w] = sq; }
  __syncthreads();
  sum = redS[0] + redS[1] + redS[2] + redS[3];
  sq = redQ[0] + redQ[1] + redQ[2] + redQ[3];

  const float c = *cptr;
  const float sqrtc = sqrtf(c);
  const float anorm = sqrtf(sq) / sum;       // |attn|
  const float an = fmaxf(anorm, 1e-5f);      // expmap0 clamp
  const float t = tanhf(sqrtc * an) / (sqrtc * an);
  const float pn = fmaxf(t * anorm, 1e-5f);  // |expmap0(attn)| (project clamp)
  const float maxn = (1.0f - 4e-3f) / sqrtc;
  const float g = t * (pn > maxn ? maxn / pn : 1.0f) / sum;

#pragma unroll
  for (int i = 0; i < 4; ++i) {
    v[i].x *= g; v[i].y *= g; v[i].z *= g; v[i].w *= g;
    reinterpret_cast<float4*>(rp)[i * 256 + tid] = v[i];
  }
}

extern "C" void kernel_launch(void* const* d_in, const int* in_sizes, int n_in,
                              void* d_out, int out_size, void* d_ws, size_t ws_size,
                              hipStream_t stream) {
  const float* query = (const float*)d_in[0];
  const float* context = (const float*)d_in[1];
  const float* W = (const float*)d_in[2];
  const float* cptr = (const float*)d_in[3];

  const int d = 1024;
  const int n = in_sizes[0] / d;  // 4096
  const int m = in_sizes[1] / d;  // 4096

  ushort_t* qn = (ushort_t*)d_ws;     // n*d bf16, row-major
  ushort_t* cn = qn + (size_t)n * d;  // m*d
  ushort_t* Wb = cn + (size_t)m * d;  // d*d
  ushort_t* qw = Wb + (size_t)d * d;  // n*d
  float* scores = (float*)d_out;      // n*m fp32, softmaxed in place

  prep_rows<<<n + m + d * d / 1024, 256, 0, stream>>>(query, context, W, qn, cn, Wb, cptr, n, m);
  // qw = qn @ Wb^T : grid (64,16)=1024 blocks
  gemm_qw<<<dim3(n / 64, d / 64), 256, 0, stream>>>(qn, Wb, qw, d, d);
  // scores = qw @ cn^T : grid (32,32)=1024 blocks
  gemm_sc<<<dim3(n / 128, m / 128), 256, 0, stream>>>(qw, cn, scores, d, m);
  softmax_hyp<<<n, 256, 0, stream>>>(scores, cptr, 1.0f / (float)d);
}

// Round 10
// 170.681 us; speedup vs baseline: 1.1000x; 1.0158x over previous
//
#include <hip/hip_runtime.h>
#include <cstdint>

// HypHawkes: attn = project(expmap0(softmax((project(expmap0(q))@W.T) @ project(expmap0(ctx)).T / d)))
// R10 = R9 + bf16 intermediate scores:
//   gemm_sc stores scores as bf16 (halves its write traffic), softmax_hyp reads bf16
//   and writes final fp32 to d_out (halves its read traffic). Error budget: bf16 on
//   raw scores (range ~+/-2) costs |Δattn| ~ 2e-9 << 4.88e-6 threshold (exp in fp32).
//   ws overlay: scores alias the dead qn/Wb region after gemm_qw (total ws 64MB).
// Frozen from R9: no __launch_bounds__ on GEMMs (LB(256) inflates VGPR 56->68 and
// triples K-loop VALU — measured r3/r5/r7/r8 vs r1/r9), r1 staging shape, BK=32.

typedef unsigned short ushort_t;
typedef __bf16 bf16x8 __attribute__((ext_vector_type(8)));
typedef float f32x4 __attribute__((ext_vector_type(4)));

__device__ __forceinline__ unsigned short f32_to_bf16(float f) {
  unsigned int u = __float_as_uint(f);
  u = (u + 0x7fffu + ((u >> 16) & 1u)) >> 16;  // RNE; inputs are finite
  return (unsigned short)u;
}

__device__ __forceinline__ void async_copy16(const void* g, void* s) {
  __builtin_amdgcn_global_load_lds(
      (const __attribute__((address_space(1))) void*)g,
      (__attribute__((address_space(3))) void*)s, 16, 0, 0);
}

// ---------------- fused prep: rownorm+expmap+project for q/ctx, cvt for W ---
// blocks [0,n): q rows; [n,n+m): ctx rows; [n+m, ...): W cvt (1024 floats each)
__global__ void prep_rows(const float* __restrict__ q, const float* __restrict__ ctx,
                          const float* __restrict__ W, ushort_t* __restrict__ qn,
                          ushort_t* __restrict__ cn, ushort_t* __restrict__ Wb,
                          const float* __restrict__ cptr, int n, int m) {
  const int b = blockIdx.x;
  const int tid = threadIdx.x;

  if (b >= n + m) {  // W conversion chunk
    int i = (b - n - m) * 256 + tid;
    float4 v = reinterpret_cast<const float4*>(W)[i];
    reinterpret_cast<ushort4*>(Wb)[i] =
        make_ushort4(f32_to_bf16(v.x), f32_to_bf16(v.y), f32_to_bf16(v.z), f32_to_bf16(v.w));
    return;
  }

  const int lane = tid & 63, w = tid >> 6;
  __shared__ float red[4];
  const float* x = (b < n) ? q + (size_t)b * 1024 : ctx + (size_t)(b - n) * 1024;
  ushort_t* out = (b < n) ? qn + (size_t)b * 1024 : cn + (size_t)(b - n) * 1024;

  float4 v = reinterpret_cast<const float4*>(x)[tid];
  float ss = v.x * v.x + v.y * v.y + v.z * v.z + v.w * v.w;
#pragma unroll
  for (int o = 32; o; o >>= 1) ss += __shfl_down(ss, o, 64);
  if (lane == 0) red[w] = ss;
  __syncthreads();
  ss = red[0] + red[1] + red[2] + red[3];

  const float c = *cptr;
  const float sqrtc = sqrtf(c);
  const float norm = fmaxf(sqrtf(ss), 1e-5f);            // expmap0 u_norm clamp
  const float t = tanhf(sqrtc * norm) / (sqrtc * norm);  // expmap scale
  const float en = fmaxf(t * norm, 1e-5f);               // |expmap0(u)| (project clamp)
  const float maxn = (1.0f - 4e-3f) / sqrtc;
  const float s = t * (en > maxn ? maxn / en : 1.0f);

  reinterpret_cast<ushort4*>(out)[tid] =
      make_ushort4(f32_to_bf16(v.x * s), f32_to_bf16(v.y * s),
                   f32_to_bf16(v.z * s), f32_to_bf16(v.w * s));
}

// ---------------- gemm1: qw = qn @ Wb^T, bf16 out -------------------------
// TM=TN=64, BK=32, grid (64,16)=1024 blocks. r1-style inline staging. 8KB LDS.
__global__ void gemm_qw(const ushort_t* __restrict__ A,
                        const ushort_t* __restrict__ B,
                        ushort_t* __restrict__ Cb, int K, int N) {
  __shared__ __align__(16) ushort_t As[64 * 32];
  __shared__ __align__(16) ushort_t Bs[64 * 32];

  const int tid = threadIdx.x;
  const int w = tid >> 6;
  const int lane = tid & 63;
  const int lane15 = lane & 15;
  const int quad = lane >> 4;
  const int wr = w >> 1, wc = w & 1;

  const size_t rowBase = (size_t)blockIdx.x * 64;
  const size_t colBase = (size_t)blockIdx.y * 64;

  const int srow = lane >> 2;        // 0..15
  const int scolE = (lane & 3) * 8;  // 0,8,16,24
  const ushort_t* Ag = A + (rowBase + (size_t)(w * 16 + srow)) * K + scolE;
  const ushort_t* Bg = B + (colBase + (size_t)(w * 16 + srow)) * K + scolE;
  ushort_t* AsD = &As[w * 512];
  ushort_t* BsD = &Bs[w * 512];

  f32x4 acc[2][2];
#pragma unroll
  for (int i = 0; i < 2; ++i)
#pragma unroll
    for (int j = 0; j < 2; ++j) acc[i][j] = f32x4{0.f, 0.f, 0.f, 0.f};

  for (int k0 = 0; k0 < K; k0 += 32) {
    async_copy16(Ag + k0, AsD);
    async_copy16(Bg + k0, BsD);
    __syncthreads();

    bf16x8 af[2], bv[2];
#pragma unroll
    for (int i = 0; i < 2; ++i) {
      af[i] = *reinterpret_cast<const bf16x8*>(&As[(wr * 32 + i * 16 + lane15) * 32 + quad * 8]);
      bv[i] = *reinterpret_cast<const bf16x8*>(&Bs[(wc * 32 + i * 16 + lane15) * 32 + quad * 8]);
    }
#pragma unroll
    for (int i = 0; i < 2; ++i)
#pragma unroll
      for (int j = 0; j < 2; ++j)
        acc[i][j] = __builtin_amdgcn_mfma_f32_16x16x32_bf16(af[i], bv[j], acc[i][j], 0, 0, 0);
    __syncthreads();
  }

  // C/D layout: col = lane&15, row = quad*4 + reg
#pragma unroll
  for (int i = 0; i < 2; ++i)
#pragma unroll
    for (int j = 0; j < 2; ++j)
#pragma unroll
      for (int r = 0; r < 4; ++r) {
        size_t row = rowBase + (size_t)(wr * 32 + i * 16 + quad * 4 + r);
        size_t col = colBase + (size_t)(wc * 32 + j * 16 + lane15);
        Cb[row * N + col] = f32_to_bf16(acc[i][j][r]);
      }
}

// ---------------- gemm2: scoresB = bf16(qw @ cn^T) -------------------------
// r1 structure (VGPR 56, ~53us): TM=TN=128, BK=32, 16KB LDS. bf16 score stores.
__global__ void gemm_sc(const ushort_t* __restrict__ A,
                        const ushort_t* __restrict__ B,
                        ushort_t* __restrict__ Sb, int K, int N) {
  __shared__ __align__(16) ushort_t As[128 * 32];
  __shared__ __align__(16) ushort_t Bs[128 * 32];

  const int tid = threadIdx.x;
  const int w = tid >> 6;
  const int lane = tid & 63;
  const int lane15 = lane & 15;
  const int quad = lane >> 4;
  const int wr = w >> 1, wc = w & 1;

  const size_t rowBase = (size_t)blockIdx.x * 128;
  const size_t colBase = (size_t)blockIdx.y * 128;

  const int srow = lane >> 2;        // 0..15
  const int scolE = (lane & 3) * 8;  // 0,8,16,24
  const ushort_t* Ag = A + (rowBase + (size_t)(w * 32 + srow)) * K + scolE;
  const ushort_t* Bg = B + (colBase + (size_t)(w * 32 + srow)) * K + scolE;
  ushort_t* AsD = &As[(w * 2) * 512];
  ushort_t* BsD = &Bs[(w * 2) * 512];

  f32x4 acc[4][4];
#pragma unroll
  for (int i = 0; i < 4; ++i)
#pragma unroll
    for (int j = 0; j < 4; ++j) acc[i][j] = f32x4{0.f, 0.f, 0.f, 0.f};

  for (int k0 = 0; k0 < K; k0 += 32) {
    async_copy16(Ag + k0, AsD);
    async_copy16(Ag + (size_t)16 * K + k0, AsD + 512);
    async_copy16(Bg + k0, BsD);
    async_copy16(Bg + (size_t)16 * K + k0, BsD + 512);
    __syncthreads();

    bf16x8 af[4], bv[4];
#pragma unroll
    for (int i = 0; i < 4; ++i) {
      af[i] = *reinterpret_cast<const bf16x8*>(&As[(wr * 64 + i * 16 + lane15) * 32 + quad * 8]);
      bv[i] = *reinterpret_cast<const bf16x8*>(&Bs[(wc * 64 + i * 16 + lane15) * 32 + quad * 8]);
    }
#pragma unroll
    for (int i = 0; i < 4; ++i)
#pragma unroll
      for (int j = 0; j < 4; ++j)
        acc[i][j] = __builtin_amdgcn_mfma_f32_16x16x32_bf16(af[i], bv[j], acc[i][j], 0, 0, 0);
    __syncthreads();
  }

  // C/D layout: col = lane&15, row = quad*4 + reg; bf16 stores (half the bytes)
#pragma unroll
  for (int i = 0; i < 4; ++i)
#pragma unroll
    for (int j = 0; j < 4; ++j)
#pragma unroll
      for (int r = 0; r < 4; ++r) {
        size_t row = rowBase + (size_t)(wr * 64 + i * 16 + quad * 4 + r);
        size_t col = colBase + (size_t)(wc * 64 + j * 16 + lane15);
        Sb[row * N + col] = f32_to_bf16(acc[i][j][r]);
      }
}

// ---------------- softmax(row/d) + expmap0 + project: bf16 in, fp32 out ----
// No max pass: logits = scores/1024 are ~+/-2e-3; exp cannot overflow and
// max-subtraction is numerically irrelevant at the output tolerance.
__global__ void softmax_hyp(const ushort_t* __restrict__ S, float* __restrict__ out,
                            const float* __restrict__ cptr, float invd) {
  const int tid = threadIdx.x;
  const int lane = tid & 63, w = tid >> 6;
  __shared__ float redS[4], redQ[4];
  const ushort_t* rp = S + (size_t)blockIdx.x * 4096;
  float* op = out + (size_t)blockIdx.x * 4096;

  float e[16];
  float sum = 0.f, sq = 0.f;
#pragma unroll
  for (int i = 0; i < 2; ++i) {
    uint4 u = reinterpret_cast<const uint4*>(rp)[i * 256 + tid];  // 8 bf16
    unsigned int uw[4] = {u.x, u.y, u.z, u.w};
#pragma unroll
    for (int k = 0; k < 4; ++k) {
      float lo = __uint_as_float(uw[k] << 16);
      float hi = __uint_as_float(uw[k] & 0xffff0000u);
      float elo = __expf(lo * invd);
      float ehi = __expf(hi * invd);
      e[i * 8 + k * 2] = elo;
      e[i * 8 + k * 2 + 1] = ehi;
      sum += elo + ehi;
      sq += elo * elo + ehi * ehi;
    }
  }
#pragma unroll
  for (int o = 32; o; o >>= 1) {
    sum += __shfl_down(sum, o, 64);
    sq += __shfl_down(sq, o, 64);
  }
  if (lane == 0) { redS[w] = sum; redQ[w] = sq; }
  __syncthreads();
  sum = redS[0] + redS[1] + redS[2] + redS[3];
  sq = redQ[0] + redQ[1] + redQ[2] + redQ[3];

  const float c = *cptr;
  const float sqrtc = sqrtf(c);
  const float anorm = sqrtf(sq) / sum;       // |attn|
  const float an = fmaxf(anorm, 1e-5f);      // expmap0 clamp
  const float t = tanhf(sqrtc * an) / (sqrtc * an);
  const float pn = fmaxf(t * anorm, 1e-5f);  // |expmap0(attn)| (project clamp)
  const float maxn = (1.0f - 4e-3f) / sqrtc;
  const float g = t * (pn > maxn ? maxn / pn : 1.0f) / sum;

#pragma unroll
  for (int i = 0; i < 2; ++i)
#pragma unroll
    for (int k = 0; k < 2; ++k) {
      float4 o = make_float4(e[i * 8 + k * 4] * g, e[i * 8 + k * 4 + 1] * g,
                             e[i * 8 + k * 4 + 2] * g, e[i * 8 + k * 4 + 3] * g);
      reinterpret_cast<float4*>(op)[(i * 256 + tid) * 2 + k] = o;
    }
}

extern "C" void kernel_launch(void* const* d_in, const int* in_sizes, int n_in,
                              void* d_out, int out_size, void* d_ws, size_t ws_size,
                              hipStream_t stream) {
  const float* query = (const float*)d_in[0];
  const float* context = (const float*)d_in[1];
  const float* W = (const float*)d_in[2];
  const float* cptr = (const float*)d_in[3];

  const int d = 1024;
  const int n = in_sizes[0] / d;  // 4096
  const int m = in_sizes[1] / d;  // 4096

  // ws overlay (total 64MB): [cn 16MB][qw 16MB][qn 16MB][Wb 2MB]; after gemm_qw,
  // qn/Wb are dead and scoresB (32MB) reuses bytes [32MB, 64MB).
  ushort_t* cn = (ushort_t*)d_ws;            // m*d bf16
  ushort_t* qw = cn + (size_t)m * d;         // n*d
  ushort_t* qn = qw + (size_t)n * d;         // n*d (dead after gemm_qw)
  ushort_t* Wb = qn + (size_t)n * d;         // d*d (dead after gemm_qw)
  ushort_t* scoresB = qn;                    // n*m bf16, aliases qn+Wb region
  float* attn = (float*)d_out;               // n*m fp32 final output

  prep_rows<<<n + m + d * d / 1024, 256, 0, stream>>>(query, context, W, qn, cn, Wb, cptr, n, m);
  // qw = qn @ Wb^T : grid (64,16)=1024 blocks
  gemm_qw<<<dim3(n / 64, d / 64), 256, 0, stream>>>(qn, Wb, qw, d, d);
  // scoresB = bf16(qw @ cn^T) : grid (32,32)=1024 blocks
  gemm_sc<<<dim3(n / 128, m / 128), 256, 0, stream>>>(qw, cn, scoresB, d, m);
  softmax_hyp<<<n, 256, 0, stream>>>(scoresB, attn, cptr, 1.0f / (float)d);
}